// Round 3
// baseline (7678.519 us; speedup 1.0000x reference)
//
#include <hip/hip_runtime.h>
#include <hip/hip_bf16.h>

// ---------------------------------------------------------------------------
// Persistent fused 2-layer GRU + head for MI355X (gfx950).
//
// R2 -> R3 changes (theory: per-step cost was dominated by 256 agent-scope
// cache-maintenance ops -- buffer_wbl2 + buffer_inv per block per step):
//  * FENCE-FREE design: all cross-block traffic (h exchange + flags) uses
//    relaxed agent-scope atomics (sc0 sc1 -> MALL-coherent, bypasses the
//    non-coherent per-XCD L2s). Zero wbl2/inv in the loop.
//  * Barrier: flag array (block stores flag[gh]=s+1; wave0's 32 lanes poll
//    all flags with one coalesced load + __all). No atomic RMW serialization.
//    Ordering by __syncthreads (vmcnt(0) drain) before the flag store.
//  * Weight LDS re-laid out fragment-major [gate][kc][lane][8]: every
//    ds_read_b128 is base+lane*16B -> zero bank conflicts.
// ---------------------------------------------------------------------------

namespace {
constexpr int kB  = 256;   // batch
constexpr int kT  = 512;   // time steps
constexpr int kF  = 32;    // input features
constexpr int kH  = 512;   // hidden
constexpr int kE  = 32;    // embed dim
constexpr int kPD = 30;    // predict days

constexpr int GBLK = 128;  // 4 batch groups x 32 hidden groups
constexpr int NTHR = 256;  // 4 waves
constexpr int HB   = 16;   // hidden slice per block
constexpr int BB   = 64;   // batch slice per block (16 per wave)

// fragment-major weight LDS: w0s[3][17][64][8], w1s[6][16][64][8] (bf16)
constexpr int L0F  = 3 * 17;           // L0 fragments per lane-set
constexpr int L1F  = 6 * 16;           // L1 fragments (3 h-gates + 3 x-gates)
constexpr int LDSB = (L0F + L1F) * 64 * 8 * 2;  // 150528 bytes
static_assert(LDSB <= 160 * 1024, "LDS overflow");

typedef __bf16 bf16_t;
typedef __bf16 bf16x8 __attribute__((ext_vector_type(8)));
typedef float  f32x4  __attribute__((ext_vector_type(4)));

__device__ __forceinline__ float sigmoid_f(float x) {
  return 1.f / (1.f + __expf(-x));
}
__device__ __forceinline__ float tanh_f(float x) {
  float a = fabsf(x);
  float e = __expf(-2.f * a);          // e in (0,1], never overflows
  float t = (1.f - e) / (1.f + e);
  return copysignf(t, x);
}

// MALL-coherent 16B load (2x sc1 dwordx2; relaxed agent atomics -> no fences)
__device__ __forceinline__ bf16x8 ld16_mall(const bf16_t* p) {
  const unsigned long long* q = (const unsigned long long*)p;
  unsigned long long lo =
      __hip_atomic_load(q, __ATOMIC_RELAXED, __HIP_MEMORY_SCOPE_AGENT);
  unsigned long long hi =
      __hip_atomic_load(q + 1, __ATOMIC_RELAXED, __HIP_MEMORY_SCOPE_AGENT);
  union { unsigned long long u[2]; bf16x8 v; } x;
  x.u[0] = lo; x.u[1] = hi;
  return x.v;
}
// MALL-coherent 2B store
__device__ __forceinline__ void st2_mall(bf16_t* p, float v) {
  bf16_t b = (bf16_t)v;
  unsigned short bits = __builtin_bit_cast(unsigned short, b);
  __hip_atomic_store((unsigned short*)p, bits, __ATOMIC_RELAXED,
                     __HIP_MEMORY_SCOPE_AGENT);
}
}  // namespace

// ws layout (bytes):
//   [0,1024)                 : 4 groups x 64 dwords of flags (32 used each)
//   h0b: 2 * B*H bf16 (512KB): layer0 output exchange, double buffered
//   h1b: 2 * B*H bf16 (512KB): layer1 hidden exchange, double buffered
//   h1f: B*H fp32     (512KB): final h1 (written once, normal stores)

__launch_bounds__(NTHR, 1)
__global__ void gru_persistent(
    const float* __restrict__ seq,
    const float* __restrict__ Wih0, const float* __restrict__ Whh0,
    const float* __restrict__ bih0, const float* __restrict__ bhh0,
    const float* __restrict__ Wih1, const float* __restrict__ Whh1,
    const float* __restrict__ bih1, const float* __restrict__ bhh1,
    bf16_t* __restrict__ h0b, bf16_t* __restrict__ h1b,
    float* __restrict__ h1f, unsigned* __restrict__ barbase) {
  extern __shared__ char smem[];
  bf16_t* w0s = (bf16_t*)smem;                    // [3][17][64][8]
  bf16_t* w1s = (bf16_t*)(smem + L0F * 512 * 2);  // [6][16][64][8]

  const int tid  = threadIdx.x;
  const int gb   = blockIdx.x & 3;    // batch group
  const int gh   = blockIdx.x >> 2;   // hidden group
  const int hs   = gh * HB;
  const int wv   = tid >> 6;
  const int lane = tid & 63;
  const int bm   = gb * BB + wv * 16; // this wave's batch-row base
  const int lm   = lane & 15;
  const int lq   = lane >> 4;
  const int koff = lq * 8;
  unsigned* flg = barbase + gb * 64;  // this group's 32 flags

  // ---- one-time: stage weights into fragment-major LDS (bf16) ----
  // w0s[g][kc][l][j] = W0(row g*512+hs+(l&15), k = kc*32+(l>>4)*8+j)
  for (int idx = tid; idx < L0F * 512; idx += NTHR) {
    const int j = idx & 7, l = (idx >> 3) & 63, rest = idx >> 9;
    const int kc = rest % 17, g = rest / 17;
    const int col = hs + (l & 15);
    const int k = kc * 32 + (l >> 4) * 8 + j;
    const int row = g * kH + col;
    float v = (k < kH) ? Whh0[row * kH + k] : Wih0[row * kF + (k - kH)];
    w0s[idx] = (bf16_t)v;
  }
  // w1s[g][kc][l][j]: g<3 -> Whh1 gate g; g>=3 -> Wih1 gate g-3 (same k)
  for (int idx = tid; idx < L1F * 512; idx += NTHR) {
    const int j = idx & 7, l = (idx >> 3) & 63, rest = idx >> 9;
    const int kc = rest & 15, g = rest >> 4;
    const int col = hs + (l & 15);
    const int k = kc * 32 + (l >> 4) * 8 + j;
    const int row = (g % 3) * kH + col;
    float v = (g < 3) ? Whh1[row * kH + k] : Wih1[row * kH + k];
    w1s[idx] = (bf16_t)v;
  }

  const int c = hs + lm;              // this lane's hidden column
  const float b0r  = bih0[c] + bhh0[c];
  const float b0z  = bih0[kH + c] + bhh0[kH + c];
  const float b0nx = bih0[2 * kH + c];
  const float b0nh = bhh0[2 * kH + c];
  const float b1r  = bih1[c] + bhh1[c];
  const float b1z  = bih1[kH + c] + bhh1[kH + c];
  const float b1nx = bih1[2 * kH + c];
  const float b1nh = bhh1[2 * kH + c];

  float h0m[4] = {0.f, 0.f, 0.f, 0.f};   // register master state
  float h1m[4] = {0.f, 0.f, 0.f, 0.f};

  __syncthreads();

  const int arow  = bm + lm;
  const int arowH = arow * kH;

#define FRAG0(g, kc) (*(const bf16x8*)(w0s + (((g)*17 + (kc)) * 64 + lane) * 8))
#define FRAG1(g, kc) (*(const bf16x8*)(w1s + (((g)*16 + (kc)) * 64 + lane) * 8))

  for (int s = 0; s <= kT; ++s) {
    const int pr = (s + 1) & 1;       // read parity (prev step)
    const int pw = s & 1;             // write parity

    // ================= layer 0 : t = s =================
    if (s < kT) {
      const float* xp = seq + ((size_t)arow * kT + s) * kF + koff;
      bf16x8 ax;
#pragma unroll
      for (int j = 0; j < 8; ++j) ax[j] = (bf16_t)xp[j];

      const bf16_t* hsrc = h0b + pr * (kB * kH);
      f32x4 aR{0.f, 0.f, 0.f, 0.f}, aZ{0.f, 0.f, 0.f, 0.f};
      f32x4 aNH{0.f, 0.f, 0.f, 0.f}, aNX{0.f, 0.f, 0.f, 0.f};

#pragma unroll 4
      for (int kc = 0; kc < 16; ++kc) {
        bf16x8 a = ld16_mall(hsrc + arowH + kc * 32 + koff);
        aR  = __builtin_amdgcn_mfma_f32_16x16x32_bf16(a, FRAG0(0, kc), aR, 0, 0, 0);
        aZ  = __builtin_amdgcn_mfma_f32_16x16x32_bf16(a, FRAG0(1, kc), aZ, 0, 0, 0);
        aNH = __builtin_amdgcn_mfma_f32_16x16x32_bf16(a, FRAG0(2, kc), aNH, 0, 0, 0);
      }
      aR  = __builtin_amdgcn_mfma_f32_16x16x32_bf16(ax, FRAG0(0, 16), aR, 0, 0, 0);
      aZ  = __builtin_amdgcn_mfma_f32_16x16x32_bf16(ax, FRAG0(1, 16), aZ, 0, 0, 0);
      aNX = __builtin_amdgcn_mfma_f32_16x16x32_bf16(ax, FRAG0(2, 16), aNX, 0, 0, 0);

      bf16_t* hnb = h0b + pw * (kB * kH);
#pragma unroll
      for (int i = 0; i < 4; ++i) {
        const int b = bm + lq * 4 + i;
        float r = sigmoid_f(aR[i] + b0r);
        float z = sigmoid_f(aZ[i] + b0z);
        float n = tanh_f((aNX[i] + b0nx) + r * (aNH[i] + b0nh));
        float hn = (1.f - z) * n + z * h0m[i];
        h0m[i] = hn;
        st2_mall(hnb + b * kH + c, hn);
      }
    }

    // ================= layer 1 : t = s-1 =================
    if (s >= 1) {
      const bf16_t* h1src = h1b + pr * (kB * kH);   // h1_{t-1}
      const bf16_t* xsrc  = h0b + pr * (kB * kH);   // out0_t
      f32x4 cR{0.f, 0.f, 0.f, 0.f}, cZ{0.f, 0.f, 0.f, 0.f};
      f32x4 cNH{0.f, 0.f, 0.f, 0.f}, cNX{0.f, 0.f, 0.f, 0.f};

#pragma unroll 4
      for (int kc = 0; kc < 16; ++kc) {
        bf16x8 a1 = ld16_mall(h1src + arowH + kc * 32 + koff);
        bf16x8 a0 = ld16_mall(xsrc + arowH + kc * 32 + koff);
        cR  = __builtin_amdgcn_mfma_f32_16x16x32_bf16(a1, FRAG1(0, kc), cR, 0, 0, 0);
        cZ  = __builtin_amdgcn_mfma_f32_16x16x32_bf16(a1, FRAG1(1, kc), cZ, 0, 0, 0);
        cNH = __builtin_amdgcn_mfma_f32_16x16x32_bf16(a1, FRAG1(2, kc), cNH, 0, 0, 0);
        cR  = __builtin_amdgcn_mfma_f32_16x16x32_bf16(a0, FRAG1(3, kc), cR, 0, 0, 0);
        cZ  = __builtin_amdgcn_mfma_f32_16x16x32_bf16(a0, FRAG1(4, kc), cZ, 0, 0, 0);
        cNX = __builtin_amdgcn_mfma_f32_16x16x32_bf16(a0, FRAG1(5, kc), cNX, 0, 0, 0);
      }
      bf16_t* hnb = h1b + pw * (kB * kH);
#pragma unroll
      for (int i = 0; i < 4; ++i) {
        const int b = bm + lq * 4 + i;
        float r = sigmoid_f(cR[i] + b1r);
        float z = sigmoid_f(cZ[i] + b1z);
        float n = tanh_f((cNX[i] + b1nx) + r * (cNH[i] + b1nh));
        float hn = (1.f - z) * n + z * h1m[i];
        h1m[i] = hn;
        if (s < kT) {
          st2_mall(hnb + b * kH + c, hn);
        } else {
          h1f[b * kH + c] = hn;  // final hidden, normal store (kernel-end release)
        }
      }
    }

    // ============ fence-free flag barrier (32 blocks / group) ============
    if (s < kT) {
      __syncthreads();  // drains every wave's sc1 stores (vmcnt(0) + s_barrier)
      if (tid == 0)
        __hip_atomic_store(flg + gh, (unsigned)(s + 1), __ATOMIC_RELAXED,
                           __HIP_MEMORY_SCOPE_AGENT);
      if (wv == 0) {
        const unsigned tgt = (unsigned)(s + 1);
        unsigned* fp = flg + (lane & 31);
        long guard = 0;
        for (;;) {
          unsigned v = __hip_atomic_load(fp, __ATOMIC_RELAXED,
                                         __HIP_MEMORY_SCOPE_AGENT);
          if (__all((int)(v >= tgt))) break;
          __builtin_amdgcn_s_sleep(1);
          if (++guard > (1L << 20)) break;  // safety valve
        }
      }
      __syncthreads();
    }
  }
#undef FRAG0
#undef FRAG1
}

// ---- head: concat(h1_last, embed) -> fc1+relu -> fc2 ----
__global__ void head_kernel(const float* __restrict__ h1,
                            const int* __restrict__ ticker,
                            const float* __restrict__ etab,
                            const float* __restrict__ fc1w,
                            const float* __restrict__ fc1b,
                            const float* __restrict__ fc2w,
                            const float* __restrict__ fc2b,
                            float* __restrict__ out) {
  __shared__ float xin[4][kH + kE];
  __shared__ float y1[4][kH];
  const int tid = threadIdx.x;
  const int b0 = blockIdx.x * 4;

  for (int idx = tid; idx < 4 * (kH + kE); idx += 256) {
    const int r = idx / (kH + kE), k = idx % (kH + kE);
    const int b = b0 + r;
    xin[r][k] = (k < kH) ? h1[b * kH + k] : etab[ticker[b] * kE + (k - kH)];
  }
  __syncthreads();

#pragma unroll
  for (int jj = 0; jj < 2; ++jj) {
    const int j = tid + jj * 256;
    const float* wr = fc1w + j * (kH + kE);
    float a0 = 0.f, a1 = 0.f, a2 = 0.f, a3 = 0.f;
    for (int k = 0; k < kH + kE; ++k) {
      const float w = wr[k];
      a0 += w * xin[0][k];
      a1 += w * xin[1][k];
      a2 += w * xin[2][k];
      a3 += w * xin[3][k];
    }
    const float bb = fc1b[j];
    y1[0][j] = fmaxf(a0 + bb, 0.f);
    y1[1][j] = fmaxf(a1 + bb, 0.f);
    y1[2][j] = fmaxf(a2 + bb, 0.f);
    y1[3][j] = fmaxf(a3 + bb, 0.f);
  }
  __syncthreads();

  if (tid < 4 * kPD) {
    const int r = tid / kPD, j = tid % kPD;
    const float* wr = fc2w + j * kH;
    float acc = fc2b[j];
    for (int k = 0; k < kH; ++k) acc += wr[k] * y1[r][k];
    out[(b0 + r) * kPD + j] = acc;
  }
}

extern "C" void kernel_launch(void* const* d_in, const int* in_sizes, int n_in,
                              void* d_out, int out_size, void* d_ws,
                              size_t ws_size, hipStream_t stream) {
  (void)in_sizes; (void)n_in; (void)out_size; (void)ws_size;

  const int*   ticker = (const int*)d_in[0];
  const float* seq    = (const float*)d_in[1];
  const float* etab   = (const float*)d_in[2];
  const float* Wih0   = (const float*)d_in[3];
  const float* Whh0   = (const float*)d_in[4];
  const float* bih0   = (const float*)d_in[5];
  const float* bhh0   = (const float*)d_in[6];
  const float* Wih1   = (const float*)d_in[7];
  const float* Whh1   = (const float*)d_in[8];
  const float* bih1   = (const float*)d_in[9];
  const float* bhh1   = (const float*)d_in[10];
  const float* fc1w   = (const float*)d_in[11];
  const float* fc1b   = (const float*)d_in[12];
  const float* fc2w   = (const float*)d_in[13];
  const float* fc2b   = (const float*)d_in[14];

  char* ws = (char*)d_ws;
  unsigned* bar = (unsigned*)ws;
  bf16_t* h0b = (bf16_t*)(ws + 1024);
  bf16_t* h1b = (bf16_t*)(ws + 1024 + 2 * kB * kH * 2);
  float*  h1f = (float*)(ws + 1024 + 4 * kB * kH * 2);
  const size_t init_bytes = 1024 + 4 * kB * kH * 2;

  hipMemsetAsync(d_ws, 0, init_bytes, stream);

  gru_persistent<<<GBLK, NTHR, LDSB, stream>>>(
      seq, Wih0, Whh0, bih0, bhh0, Wih1, Whh1, bih1, bhh1,
      h0b, h1b, h1f, bar);

  head_kernel<<<kB / 4, 256, 0, stream>>>(h1f, ticker, etab, fc1w, fc1b, fc2w,
                                          fc2b, (float*)d_out);
}

// Round 5
// 3471.084 us; speedup vs baseline: 2.2121x; 2.2121x over previous
//
#include <hip/hip_runtime.h>
#include <hip/hip_bf16.h>

// ---------------------------------------------------------------------------
// Persistent fused 2-layer GRU + head for MI355X (gfx950).
//
// R4 -> R5: compile fix only (missing `}  // namespace`). Design as R4:
// XCD-LOCAL exchange. R3's counters showed the h exchange round-tripping
// through HBM (WRITE 515 KB/step, FETCH 580 KB/step: sc1 stores are
// no-write-allocate at MALL). Fix: 8 batch groups x 32 rows, one group per
// XCD (blocks self-identify via HW_REG_XCC_ID and grab a per-XCD slot), so
// producers+consumers of every h line share one coherent L2. Exchange =
// plain L2 load/store; per-step `buffer_inv` (L1-only inv, L1 is
// write-through) gives freshness. Barrier = flag lines in the XCD's L2.
// Startup check falls back to a MALL path (R3-style) if the 32/XCD
// dispatch assumption fails -- correctness never depends on the heuristic.
// Wave roles: w0=L0 (B-frag reused across 2 row-tiles), w1=L1 h-part,
// w3=L1 x-part (partials via LDS), w2=barrier manager.
// ---------------------------------------------------------------------------

namespace {
constexpr int kB  = 256;   // batch
constexpr int kT  = 512;   // time steps
constexpr int kF  = 32;    // input features
constexpr int kH  = 512;   // hidden
constexpr int kE  = 32;    // embed dim
constexpr int kPD = 30;    // predict days

constexpr int GBLK = 256;  // 8 XCD groups x 32 hidden slots, 1 block/CU
constexpr int NTHR = 256;  // 4 waves
constexpr int RG   = 32;   // batch rows per group
constexpr int HB   = 16;   // hidden cols per block

// fragment-major weight LDS: w0s[3][17][64][8], w1s[6][16][64][8] (bf16)
constexpr int L0F  = 3 * 17;
constexpr int L1F  = 6 * 16;
constexpr int PART_OFF = (L0F + L1F) * 512 * 2;   // 150528 B
constexpr int LDSB = PART_OFF + 6 * 64 * 16;      // + partials 6KB = 156672
static_assert(LDSB <= 160 * 1024, "LDS overflow");

// ws layout (bytes)
constexpr size_t WS_CNT   = 0;        // 8 per-XCD counters, 128B apart
constexpr size_t WS_TOTAL = 1024;     // arrival counter
constexpr size_t WS_FB    = 1152;     // fallback flag
constexpr size_t WS_FLG   = 2048;     // 8 groups x 32 slots x 128B = 32KB
constexpr size_t WS_H0B   = 65536;                    // 2*B*H bf16 = 512KB
constexpr size_t WS_H1B   = WS_H0B + 2 * kB * kH * 2; // 512KB
constexpr size_t WS_H1F   = WS_H0B + 4 * kB * kH * 2; // B*H f32 = 512KB
constexpr size_t WS_INIT  = WS_H1F;   // zero [0, WS_H1F)

typedef __bf16 bf16_t;
typedef __bf16 bf16x8 __attribute__((ext_vector_type(8)));
typedef float  f32x4  __attribute__((ext_vector_type(4)));

#define MFMA __builtin_amdgcn_mfma_f32_16x16x32_bf16

__device__ __forceinline__ float sigmoid_f(float x) {
  return 1.f / (1.f + __expf(-x));
}
__device__ __forceinline__ float tanh_f(float x) {
  float a = fabsf(x);
  float e = __expf(-2.f * a);
  float t = (1.f - e) / (1.f + e);
  return copysignf(t, x);
}

// MALL-coherent primitives (fallback path only)
__device__ __forceinline__ bf16x8 ld16_mall(const bf16_t* p) {
  const unsigned long long* q = (const unsigned long long*)p;
  unsigned long long lo =
      __hip_atomic_load(q, __ATOMIC_RELAXED, __HIP_MEMORY_SCOPE_AGENT);
  unsigned long long hi =
      __hip_atomic_load(q + 1, __ATOMIC_RELAXED, __HIP_MEMORY_SCOPE_AGENT);
  union { unsigned long long u[2]; bf16x8 v; } x;
  x.u[0] = lo; x.u[1] = hi;
  return x.v;
}
__device__ __forceinline__ void st2_mall(bf16_t* p, float v) {
  bf16_t b = (bf16_t)v;
  unsigned short bits = __builtin_bit_cast(unsigned short, b);
  __hip_atomic_store((unsigned short*)p, bits, __ATOMIC_RELAXED,
                     __HIP_MEMORY_SCOPE_AGENT);
}

template <bool XL>
__device__ __forceinline__ bf16x8 ld16x(const bf16_t* p) {
  if constexpr (XL) return *(const bf16x8*)p;
  else return ld16_mall(p);
}
template <bool XL>
__device__ __forceinline__ void st2x(bf16_t* p, float v) {
  if constexpr (XL) *p = (bf16_t)v;
  else st2_mall(p, v);
}
}  // namespace

#define FRAG0(gg, kc) (*(const bf16x8*)(w0s + (((gg)*17 + (kc)) * 64 + lane) * 8))
#define FRAG1(gg, kc) (*(const bf16x8*)(w1s + (((gg)*16 + (kc)) * 64 + lane) * 8))

template <bool XL>
__device__ void run_loop(const float* __restrict__ seq,
                         bf16_t* __restrict__ h0b, bf16_t* __restrict__ h1b,
                         float* __restrict__ h1f, unsigned* __restrict__ flg,
                         const bf16_t* __restrict__ w0s,
                         const bf16_t* __restrict__ w1s,
                         float* __restrict__ part, int g, int slot,
                         float b0r, float b0z, float b0nx, float b0nh,
                         float b1r, float b1z, float b1nx, float b1nh) {
  const int tid  = threadIdx.x;
  const int wv   = tid >> 6;
  const int lane = tid & 63;
  const int lm   = lane & 15;
  const int lq   = lane >> 4;
  const int koff = lq * 8;
  const int rbase = g * RG;
  const int c     = slot * HB + lm;
  const int ar0 = (rbase + lm) * kH;        // row-tile 0 A offset
  const int ar1 = (rbase + 16 + lm) * kH;   // row-tile 1

  float h0m[2][4] = {{0.f,0.f,0.f,0.f},{0.f,0.f,0.f,0.f}};
  float h1m[2][4] = {{0.f,0.f,0.f,0.f},{0.f,0.f,0.f,0.f}};

  for (int s = 0; s <= kT; ++s) {
    const int pr = (s + 1) & 1;
    const int pw = s & 1;

    f32x4 cR[2], cZ[2], cNH[2];   // wave1 accs (live across sync P)
#pragma unroll
    for (int rt = 0; rt < 2; ++rt) { cR[rt]=f32x4{0,0,0,0}; cZ[rt]=f32x4{0,0,0,0}; cNH[rt]=f32x4{0,0,0,0}; }

    // ---------------- phase 1: GEMMs ----------------
    if (wv == 0 && s < kT) {
      // layer 0, both row-tiles, full K (h + x), epilogue + store
      const bf16_t* hsrc = h0b + pr * (kB * kH);
      f32x4 aR[2], aZ[2], aNH[2], aNX[2];
#pragma unroll
      for (int rt = 0; rt < 2; ++rt) { aR[rt]=f32x4{0,0,0,0}; aZ[rt]=f32x4{0,0,0,0}; aNH[rt]=f32x4{0,0,0,0}; aNX[rt]=f32x4{0,0,0,0}; }
#pragma unroll 4
      for (int kc = 0; kc < 16; ++kc) {
        bf16x8 a0 = ld16x<XL>(hsrc + ar0 + kc * 32 + koff);
        bf16x8 a1 = ld16x<XL>(hsrc + ar1 + kc * 32 + koff);
        bf16x8 br = FRAG0(0, kc), bz = FRAG0(1, kc), bn = FRAG0(2, kc);
        aR[0]  = MFMA(a0, br, aR[0], 0,0,0);  aR[1]  = MFMA(a1, br, aR[1], 0,0,0);
        aZ[0]  = MFMA(a0, bz, aZ[0], 0,0,0);  aZ[1]  = MFMA(a1, bz, aZ[1], 0,0,0);
        aNH[0] = MFMA(a0, bn, aNH[0],0,0,0);  aNH[1] = MFMA(a1, bn, aNH[1],0,0,0);
      }
      {
        const float* xp0 = seq + ((size_t)(rbase + lm) * kT + s) * kF + koff;
        const float* xp1 = seq + ((size_t)(rbase + 16 + lm) * kT + s) * kF + koff;
        bf16x8 ax0, ax1;
#pragma unroll
        for (int j = 0; j < 8; ++j) { ax0[j] = (bf16_t)xp0[j]; ax1[j] = (bf16_t)xp1[j]; }
        bf16x8 br = FRAG0(0, 16), bz = FRAG0(1, 16), bn = FRAG0(2, 16);
        aR[0]  = MFMA(ax0, br, aR[0], 0,0,0);  aR[1]  = MFMA(ax1, br, aR[1], 0,0,0);
        aZ[0]  = MFMA(ax0, bz, aZ[0], 0,0,0);  aZ[1]  = MFMA(ax1, bz, aZ[1], 0,0,0);
        aNX[0] = MFMA(ax0, bn, aNX[0],0,0,0);  aNX[1] = MFMA(ax1, bn, aNX[1],0,0,0);
      }
      bf16_t* hnb = h0b + pw * (kB * kH);
#pragma unroll
      for (int rt = 0; rt < 2; ++rt)
#pragma unroll
        for (int i = 0; i < 4; ++i) {
          const int row = rbase + rt * 16 + lq * 4 + i;
          float r = sigmoid_f(aR[rt][i] + b0r);
          float z = sigmoid_f(aZ[rt][i] + b0z);
          float n = tanh_f((aNX[rt][i] + b0nx) + r * (aNH[rt][i] + b0nh));
          float hn = (1.f - z) * n + z * h0m[rt][i];
          h0m[rt][i] = hn;
          st2x<XL>(hnb + row * kH + c, hn);
        }
    } else if (wv == 1 && s >= 1) {
      // layer 1 h-part (A = h1_{t-1})
      const bf16_t* hsrc = h1b + pr * (kB * kH);
#pragma unroll 4
      for (int kc = 0; kc < 16; ++kc) {
        bf16x8 a0 = ld16x<XL>(hsrc + ar0 + kc * 32 + koff);
        bf16x8 a1 = ld16x<XL>(hsrc + ar1 + kc * 32 + koff);
        bf16x8 br = FRAG1(0, kc), bz = FRAG1(1, kc), bn = FRAG1(2, kc);
        cR[0]  = MFMA(a0, br, cR[0], 0,0,0);  cR[1]  = MFMA(a1, br, cR[1], 0,0,0);
        cZ[0]  = MFMA(a0, bz, cZ[0], 0,0,0);  cZ[1]  = MFMA(a1, bz, cZ[1], 0,0,0);
        cNH[0] = MFMA(a0, bn, cNH[0],0,0,0);  cNH[1] = MFMA(a1, bn, cNH[1],0,0,0);
      }
    } else if (wv == 3 && s >= 1) {
      // layer 1 x-part (A = out0_t) -> partials to LDS
      const bf16_t* xsrc = h0b + pr * (kB * kH);
      f32x4 xR[2], xZ[2], xNX[2];
#pragma unroll
      for (int rt = 0; rt < 2; ++rt) { xR[rt]=f32x4{0,0,0,0}; xZ[rt]=f32x4{0,0,0,0}; xNX[rt]=f32x4{0,0,0,0}; }
#pragma unroll 4
      for (int kc = 0; kc < 16; ++kc) {
        bf16x8 a0 = ld16x<XL>(xsrc + ar0 + kc * 32 + koff);
        bf16x8 a1 = ld16x<XL>(xsrc + ar1 + kc * 32 + koff);
        bf16x8 br = FRAG1(3, kc), bz = FRAG1(4, kc), bn = FRAG1(5, kc);
        xR[0]  = MFMA(a0, br, xR[0], 0,0,0);  xR[1]  = MFMA(a1, br, xR[1], 0,0,0);
        xZ[0]  = MFMA(a0, bz, xZ[0], 0,0,0);  xZ[1]  = MFMA(a1, bz, xZ[1], 0,0,0);
        xNX[0] = MFMA(a0, bn, xNX[0],0,0,0);  xNX[1] = MFMA(a1, bn, xNX[1],0,0,0);
      }
#pragma unroll
      for (int rt = 0; rt < 2; ++rt) {
        *(f32x4*)(part + ((rt * 3 + 0) * 64 + lane) * 4) = xR[rt];
        *(f32x4*)(part + ((rt * 3 + 1) * 64 + lane) * 4) = xZ[rt];
        *(f32x4*)(part + ((rt * 3 + 2) * 64 + lane) * 4) = xNX[rt];
      }
    }
    __syncthreads();  // (P) partials visible; all phase-1 stores drained

    // ---------------- phase 2: layer-1 epilogue ----------------
    if (wv == 1 && s >= 1) {
      bf16_t* hnb = h1b + pw * (kB * kH);
#pragma unroll
      for (int rt = 0; rt < 2; ++rt) {
        f32x4 pR  = *(const f32x4*)(part + ((rt * 3 + 0) * 64 + lane) * 4);
        f32x4 pZ  = *(const f32x4*)(part + ((rt * 3 + 1) * 64 + lane) * 4);
        f32x4 pNX = *(const f32x4*)(part + ((rt * 3 + 2) * 64 + lane) * 4);
#pragma unroll
        for (int i = 0; i < 4; ++i) {
          const int row = rbase + rt * 16 + lq * 4 + i;
          float r = sigmoid_f(cR[rt][i] + pR[i] + b1r);
          float z = sigmoid_f(cZ[rt][i] + pZ[i] + b1z);
          float n = tanh_f((pNX[i] + b1nx) + r * (cNH[rt][i] + b1nh));
          float hn = (1.f - z) * n + z * h1m[rt][i];
          h1m[rt][i] = hn;
          if (s < kT) st2x<XL>(hnb + row * kH + c, hn);
          else        h1f[row * kH + c] = hn;
        }
      }
    }
    __syncthreads();  // (A) ALL stores of this step drained to L2/MALL

    // ---------------- barrier ----------------
    if (s < kT) {
      if (wv == 2) {
        const unsigned tgt = (unsigned)(s + 1);
        if constexpr (XL) {
          if (lane == 0) *(volatile unsigned*)(flg + slot * 32) = tgt;
          volatile unsigned* fp = flg + (lane & 31) * 32;
          long guard = 0;
          for (;;) {
            asm volatile("buffer_inv" ::: "memory");  // L1 inv -> read L2
            unsigned v = *fp;
            if (__all((int)(v >= tgt))) break;
            __builtin_amdgcn_s_sleep(1);
            if (++guard > (1L << 20)) break;
          }
        } else {
          if (lane == 0)
            __hip_atomic_store(flg + slot * 32, tgt, __ATOMIC_RELAXED,
                               __HIP_MEMORY_SCOPE_AGENT);
          unsigned* fp = flg + (lane & 31) * 32;
          long guard = 0;
          for (;;) {
            unsigned v = __hip_atomic_load(fp, __ATOMIC_RELAXED,
                                           __HIP_MEMORY_SCOPE_AGENT);
            if (__all((int)(v >= tgt))) break;
            __builtin_amdgcn_s_sleep(1);
            if (++guard > (1L << 20)) break;
          }
        }
      }
      __syncthreads();  // (B)
      if constexpr (XL)
        asm volatile("buffer_inv" ::: "memory");  // fresh L1 for next step
    }
  }
}

__launch_bounds__(NTHR, 1)
__global__ void gru_persistent(
    const float* __restrict__ seq,
    const float* __restrict__ Wih0, const float* __restrict__ Whh0,
    const float* __restrict__ bih0, const float* __restrict__ bhh0,
    const float* __restrict__ Wih1, const float* __restrict__ Whh1,
    const float* __restrict__ bih1, const float* __restrict__ bhh1,
    char* __restrict__ ws) {
  extern __shared__ char smem[];
  bf16_t* w0s = (bf16_t*)smem;
  bf16_t* w1s = (bf16_t*)(smem + L0F * 512 * 2);
  float*  part = (float*)(smem + PART_OFF);
  __shared__ unsigned sh_enc;

  const int tid = threadIdx.x;

  // ---- self-organization: group = physical XCD, slot = per-XCD ordinal ----
  if (tid == 0) {
    unsigned xcd;
    asm("s_getreg_b32 %0, hwreg(HW_REG_XCC_ID)" : "=s"(xcd));
    xcd &= 7;
    unsigned* cnt   = (unsigned*)(ws + WS_CNT) + xcd * 32;
    unsigned* total = (unsigned*)(ws + WS_TOTAL);
    unsigned* fb    = (unsigned*)(ws + WS_FB);
    unsigned slot = __hip_atomic_fetch_add(cnt, 1u, __ATOMIC_RELAXED,
                                           __HIP_MEMORY_SCOPE_AGENT);
    if (slot >= 32)
      __hip_atomic_store(fb, 1u, __ATOMIC_RELAXED, __HIP_MEMORY_SCOPE_AGENT);
    __hip_atomic_fetch_add(total, 1u, __ATOMIC_RELAXED,
                           __HIP_MEMORY_SCOPE_AGENT);
    long guard = 0;
    while (__hip_atomic_load(total, __ATOMIC_RELAXED,
                             __HIP_MEMORY_SCOPE_AGENT) < (unsigned)GBLK) {
      __builtin_amdgcn_s_sleep(1);
      if (++guard > (1L << 24)) break;
    }
    unsigned f = __hip_atomic_load(fb, __ATOMIC_RELAXED,
                                   __HIP_MEMORY_SCOPE_AGENT);
    sh_enc = (f << 31) | (xcd << 8) | (slot & 255);
  }
  __syncthreads();
  const unsigned enc = sh_enc;
  const bool fallback = (enc >> 31) != 0;
  const int g    = fallback ? (blockIdx.x & 7)  : (int)((enc >> 8) & 7);
  const int slot = fallback ? (blockIdx.x >> 3) : (int)(enc & 255);
  const int hs   = slot * HB;

  // ---- stage weights into fragment-major LDS (bf16) ----
  for (int idx = tid; idx < L0F * 512; idx += NTHR) {
    const int j = idx & 7, l = (idx >> 3) & 63, rest = idx >> 9;
    const int kc = rest % 17, gg = rest / 17;
    const int col = hs + (l & 15);
    const int k = kc * 32 + (l >> 4) * 8 + j;
    const int row = gg * kH + col;
    float v = (k < kH) ? Whh0[row * kH + k] : Wih0[row * kF + (k - kH)];
    w0s[idx] = (bf16_t)v;
  }
  for (int idx = tid; idx < L1F * 512; idx += NTHR) {
    const int j = idx & 7, l = (idx >> 3) & 63, rest = idx >> 9;
    const int kc = rest & 15, gg = rest >> 4;
    const int col = hs + (l & 15);
    const int k = kc * 32 + (l >> 4) * 8 + j;
    const int row = (gg % 3) * kH + col;
    float v = (gg < 3) ? Whh1[row * kH + k] : Wih1[row * kH + k];
    w1s[idx] = (bf16_t)v;
  }

  const int lm = tid & 15;
  const int c = hs + lm;
  const float b0r  = bih0[c] + bhh0[c];
  const float b0z  = bih0[kH + c] + bhh0[kH + c];
  const float b0nx = bih0[2 * kH + c];
  const float b0nh = bhh0[2 * kH + c];
  const float b1r  = bih1[c] + bhh1[c];
  const float b1z  = bih1[kH + c] + bhh1[kH + c];
  const float b1nx = bih1[2 * kH + c];
  const float b1nh = bhh1[2 * kH + c];

  __syncthreads();

  bf16_t* h0b = (bf16_t*)(ws + WS_H0B);
  bf16_t* h1b = (bf16_t*)(ws + WS_H1B);
  float*  h1f = (float*)(ws + WS_H1F);
  unsigned* flg = (unsigned*)(ws + WS_FLG) + g * 1024;  // 32 lines x 128B

  if (fallback)
    run_loop<false>(seq, h0b, h1b, h1f, flg, w0s, w1s, part, g, slot,
                    b0r, b0z, b0nx, b0nh, b1r, b1z, b1nx, b1nh);
  else
    run_loop<true>(seq, h0b, h1b, h1f, flg, w0s, w1s, part, g, slot,
                   b0r, b0z, b0nx, b0nh, b1r, b1z, b1nx, b1nh);
}

// ---- head: concat(h1_last, embed) -> fc1+relu -> fc2 ----
__global__ void head_kernel(const float* __restrict__ h1,
                            const int* __restrict__ ticker,
                            const float* __restrict__ etab,
                            const float* __restrict__ fc1w,
                            const float* __restrict__ fc1b,
                            const float* __restrict__ fc2w,
                            const float* __restrict__ fc2b,
                            float* __restrict__ out) {
  __shared__ float xin[4][kH + kE];
  __shared__ float y1[4][kH];
  const int tid = threadIdx.x;
  const int b0 = blockIdx.x * 4;

  for (int idx = tid; idx < 4 * (kH + kE); idx += 256) {
    const int r = idx / (kH + kE), k = idx % (kH + kE);
    const int b = b0 + r;
    xin[r][k] = (k < kH) ? h1[b * kH + k] : etab[ticker[b] * kE + (k - kH)];
  }
  __syncthreads();

#pragma unroll
  for (int jj = 0; jj < 2; ++jj) {
    const int j = tid + jj * 256;
    const float* wr = fc1w + j * (kH + kE);
    float a0 = 0.f, a1 = 0.f, a2 = 0.f, a3 = 0.f;
    for (int k = 0; k < kH + kE; ++k) {
      const float w = wr[k];
      a0 += w * xin[0][k];
      a1 += w * xin[1][k];
      a2 += w * xin[2][k];
      a3 += w * xin[3][k];
    }
    const float bb = fc1b[j];
    y1[0][j] = fmaxf(a0 + bb, 0.f);
    y1[1][j] = fmaxf(a1 + bb, 0.f);
    y1[2][j] = fmaxf(a2 + bb, 0.f);
    y1[3][j] = fmaxf(a3 + bb, 0.f);
  }
  __syncthreads();

  if (tid < 4 * kPD) {
    const int r = tid / kPD, j = tid % kPD;
    const float* wr = fc2w + j * kH;
    float acc = fc2b[j];
    for (int k = 0; k < kH; ++k) acc += wr[k] * y1[r][k];
    out[(b0 + r) * kPD + j] = acc;
  }
}

extern "C" void kernel_launch(void* const* d_in, const int* in_sizes, int n_in,
                              void* d_out, int out_size, void* d_ws,
                              size_t ws_size, hipStream_t stream) {
  (void)in_sizes; (void)n_in; (void)out_size; (void)ws_size;

  const int*   ticker = (const int*)d_in[0];
  const float* seq    = (const float*)d_in[1];
  const float* etab   = (const float*)d_in[2];
  const float* Wih0   = (const float*)d_in[3];
  const float* Whh0   = (const float*)d_in[4];
  const float* bih0   = (const float*)d_in[5];
  const float* bhh0   = (const float*)d_in[6];
  const float* Wih1   = (const float*)d_in[7];
  const float* Whh1   = (const float*)d_in[8];
  const float* bih1   = (const float*)d_in[9];
  const float* bhh1   = (const float*)d_in[10];
  const float* fc1w   = (const float*)d_in[11];
  const float* fc1b   = (const float*)d_in[12];
  const float* fc2w   = (const float*)d_in[13];
  const float* fc2b   = (const float*)d_in[14];

  char* ws = (char*)d_ws;
  (void)hipMemsetAsync(ws, 0, WS_INIT, stream);  // counters + flags + h0b + h1b

  gru_persistent<<<GBLK, NTHR, LDSB, stream>>>(
      seq, Wih0, Whh0, bih0, bhh0, Wih1, Whh1, bih1, bhh1, ws);

  head_kernel<<<kB / 4, 256, 0, stream>>>((const float*)(ws + WS_H1F), ticker,
                                          etab, fc1w, fc1b, fc2w, fc2b,
                                          (float*)d_out);
}

// Round 8
// 3457.492 us; speedup vs baseline: 2.2208x; 1.0039x over previous
//
#include <hip/hip_runtime.h>
#include <hip/hip_bf16.h>

// ---------------------------------------------------------------------------
// Persistent fused 2-layer GRU + head for MI355X (gfx950).
//
// R7 -> R8: REVERT to the R5-proven synchronization (deterministic; R7's
// sync-free per-wave-flag design was flaky under timing variation -- graph
// replay diverged from launch_once). Keep the one safe R6 lever:
//
//  * B-fragments in REGISTERS per wave role (step-invariant weights):
//      w0 = L0 row-tile 0 (51 frags) + barrier manager
//      w2 = L0 row-tile 1 (51 frags)
//      w1 = L1 h-part, both row tiles (48 frags) + L1 epilogue
//      w3 = L1 x-part, both row tiles (48 frags) -> LDS partials
//    Steady state: zero LDS reads for weights; ~250 VGPR/role (1 wave/SIMD
//    -> 512 budget). Roles are noinline functions, each executing an
//    IDENTICAL 3-__syncthreads()-per-step sequence so barrier counts match.
//  * Barrier protocol = R5 verbatim: per-block flag (128B apart) in the
//    XCD's L2; w0 stores flag s+1 after sync A, polls 32 flags with
//    buffer_inv before every volatile load; all waves buffer_inv after
//    sync B. XCD self-assignment (HW_REG_XCC_ID) + MALL fallback kept.
// ---------------------------------------------------------------------------

namespace {
constexpr int kB  = 256;   // batch
constexpr int kT  = 512;   // time steps
constexpr int kF  = 32;    // input features
constexpr int kH  = 512;   // hidden
constexpr int kE  = 32;    // embed dim
constexpr int kPD = 30;    // predict days

constexpr int GBLK = 256;  // 8 XCD groups x 32 hidden slots, 1 block/CU
constexpr int NTHR = 256;  // 4 waves
constexpr int RG   = 32;   // batch rows per group
constexpr int HB   = 16;   // hidden cols per block

// fragment-major weight staging LDS + fp32 partial-handoff buffer
constexpr int L0F  = 3 * 17;
constexpr int L1F  = 6 * 16;
constexpr int PART_OFF = (L0F + L1F) * 512 * 2;   // 150528 B
constexpr int LDSB = PART_OFF + 6 * 64 * 16;      // +6KB partials = 156672
static_assert(LDSB <= 160 * 1024, "LDS overflow");

// ws layout (bytes)
constexpr size_t WS_CNT   = 0;        // 8 per-XCD counters, 128B apart
constexpr size_t WS_TOTAL = 1024;     // arrival counter
constexpr size_t WS_FB    = 1152;     // fallback flag
constexpr size_t WS_FLG   = 2048;     // 8 groups x 32 slots x 128B = 32KB
constexpr size_t WS_H0B   = 65536;                    // 2*B*H bf16 = 512KB
constexpr size_t WS_H1B   = WS_H0B + 2 * kB * kH * 2; // 512KB
constexpr size_t WS_H1F   = WS_H0B + 4 * kB * kH * 2; // B*H f32 = 512KB
constexpr size_t WS_INIT  = WS_H1F;   // zero [0, WS_H1F)

typedef __bf16 bf16_t;
typedef __bf16 bf16x8 __attribute__((ext_vector_type(8)));
typedef float  f32x4  __attribute__((ext_vector_type(4)));

#define MFMA __builtin_amdgcn_mfma_f32_16x16x32_bf16

__device__ __forceinline__ float sigmoid_f(float x) {
  return 1.f / (1.f + __expf(-x));
}
__device__ __forceinline__ float tanh_f(float x) {
  float a = fabsf(x);
  float e = __expf(-2.f * a);
  float t = (1.f - e) / (1.f + e);
  return copysignf(t, x);
}

// MALL-coherent primitives (fallback path only)
__device__ __forceinline__ bf16x8 ld16_mall(const bf16_t* p) {
  const unsigned long long* q = (const unsigned long long*)p;
  unsigned long long lo =
      __hip_atomic_load(q, __ATOMIC_RELAXED, __HIP_MEMORY_SCOPE_AGENT);
  unsigned long long hi =
      __hip_atomic_load(q + 1, __ATOMIC_RELAXED, __HIP_MEMORY_SCOPE_AGENT);
  union { unsigned long long u[2]; bf16x8 v; } x;
  x.u[0] = lo; x.u[1] = hi;
  return x.v;
}
__device__ __forceinline__ void st2_mall(bf16_t* p, float v) {
  bf16_t b = (bf16_t)v;
  unsigned short bits = __builtin_bit_cast(unsigned short, b);
  __hip_atomic_store((unsigned short*)p, bits, __ATOMIC_RELAXED,
                     __HIP_MEMORY_SCOPE_AGENT);
}

template <bool XL>
__device__ __forceinline__ bf16x8 ld16x(const bf16_t* p) {
  if constexpr (XL) return *(const bf16x8*)p;
  else return ld16_mall(p);
}
template <bool XL>
__device__ __forceinline__ void st2x(bf16_t* p, float v) {
  if constexpr (XL) *p = (bf16_t)v;
  else st2_mall(p, v);
}

// R5-proven inter-block barrier: store own flag, poll all 32 group flags
// (one per lane, 128B apart) with buffer_inv before each volatile load.
template <bool XL>
__device__ __forceinline__ void block_flag_barrier(unsigned* flg, int slot,
                                                   int lane, unsigned tgt) {
  if constexpr (XL) {
    if (lane == 0) *(volatile unsigned*)(flg + slot * 32) = tgt;
    volatile unsigned* fp = flg + (lane & 31) * 32;
    long guard = 0;
    for (;;) {
      asm volatile("buffer_inv" ::: "memory");
      unsigned v = *fp;
      if (__all((int)(v >= tgt))) break;
      __builtin_amdgcn_s_sleep(1);
      if (++guard > (1L << 20)) break;  // co-residency guaranteed
    }
  } else {
    if (lane == 0)
      __hip_atomic_store(flg + slot * 32, tgt, __ATOMIC_RELAXED,
                         __HIP_MEMORY_SCOPE_AGENT);
    unsigned* fp = flg + (lane & 31) * 32;
    long guard = 0;
    for (;;) {
      unsigned v = __hip_atomic_load(fp, __ATOMIC_RELAXED,
                                     __HIP_MEMORY_SCOPE_AGENT);
      if (__all((int)(v >= tgt))) break;
      __builtin_amdgcn_s_sleep(1);
      if (++guard > (1L << 20)) break;
    }
  }
}
}  // namespace

#define FRAG0(gg, kc) (*(const bf16x8*)(w0s + (((gg)*17 + (kc)) * 64 + lane) * 8))
#define FRAG1(gg, kc) (*(const bf16x8*)(w1s + (((gg)*16 + (kc)) * 64 + lane) * 8))

// ---- role: layer 0, one row tile; mgr additionally runs the flag barrier ----
template <bool XL>
__device__ __attribute__((noinline)) void role_l0(
    const float* __restrict__ seq, bf16_t* __restrict__ h0b,
    unsigned* __restrict__ flg, const bf16_t* __restrict__ w0s, int slot,
    bool mgr, int lane, int rbase, int rt, int c, float b0r, float b0z,
    float b0nx, float b0nh) {
  const int lm = lane & 15, lq = lane >> 4, koff = lq * 8;
  const int arow = rbase + rt * 16 + lm;
  const int ar = arow * kH;
  bf16x8 f0[3][17];  // 51 frags = 204 VGPR, loaded once
#pragma unroll
  for (int g = 0; g < 3; ++g)
#pragma unroll
    for (int kc = 0; kc < 17; ++kc) f0[g][kc] = FRAG0(g, kc);
  float h0m[4] = {0.f, 0.f, 0.f, 0.f};

  for (int s = 0; s <= kT; ++s) {
    if (s < kT) {
      const int pr = (s + 1) & 1, pw = s & 1;
      const bf16_t* hsrc = h0b + pr * (kB * kH);
      f32x4 aR{0,0,0,0}, aZ{0,0,0,0}, aNH{0,0,0,0}, aNX{0,0,0,0};
#pragma unroll
      for (int kc = 0; kc < 16; ++kc) {
        bf16x8 a = ld16x<XL>(hsrc + ar + kc * 32 + koff);
        aR  = MFMA(a, f0[0][kc], aR, 0, 0, 0);
        aZ  = MFMA(a, f0[1][kc], aZ, 0, 0, 0);
        aNH = MFMA(a, f0[2][kc], aNH, 0, 0, 0);
      }
      {
        const float* xp = seq + ((size_t)arow * kT + s) * kF + koff;
        bf16x8 ax;
#pragma unroll
        for (int j = 0; j < 8; ++j) ax[j] = (bf16_t)xp[j];
        aR  = MFMA(ax, f0[0][16], aR, 0, 0, 0);
        aZ  = MFMA(ax, f0[1][16], aZ, 0, 0, 0);
        aNX = MFMA(ax, f0[2][16], aNX, 0, 0, 0);
      }
      bf16_t* hnb = h0b + pw * (kB * kH);
#pragma unroll
      for (int i = 0; i < 4; ++i) {
        const int row = rbase + rt * 16 + lq * 4 + i;
        float r = sigmoid_f(aR[i] + b0r);
        float z = sigmoid_f(aZ[i] + b0z);
        float n = tanh_f((aNX[i] + b0nx) + r * (aNH[i] + b0nh));
        float hn = (1.f - z) * n + z * h0m[i];
        h0m[i] = hn;
        st2x<XL>(hnb + row * kH + c, hn);
      }
    }
    __syncthreads();  // P
    __syncthreads();  // A: every wave's stores for step s drained
    if (mgr && s < kT)
      block_flag_barrier<XL>(flg, slot, lane, (unsigned)(s + 1));
    __syncthreads();  // B
    if constexpr (XL) asm volatile("buffer_inv" ::: "memory");
  }
}

// ---- role: layer 1 h-part (both row tiles) + epilogue ----
template <bool XL>
__device__ __attribute__((noinline)) void role_l1h(
    bf16_t* __restrict__ h1b, float* __restrict__ h1f,
    const bf16_t* __restrict__ w1s, const float* __restrict__ part, int lane,
    int rbase, int c, float b1r, float b1z, float b1nx, float b1nh) {
  const int lm = lane & 15, lq = lane >> 4, koff = lq * 8;
  const int ar0 = (rbase + lm) * kH, ar1 = (rbase + 16 + lm) * kH;
  bf16x8 fh[3][16];  // 48 frags = 192 VGPR
#pragma unroll
  for (int g = 0; g < 3; ++g)
#pragma unroll
    for (int kc = 0; kc < 16; ++kc) fh[g][kc] = FRAG1(g, kc);
  float h1m[2][4] = {{0,0,0,0},{0,0,0,0}};

  for (int s = 0; s <= kT; ++s) {
    f32x4 cR[2], cZ[2], cNH[2];
#pragma unroll
    for (int rt = 0; rt < 2; ++rt) {
      cR[rt] = f32x4{0,0,0,0}; cZ[rt] = f32x4{0,0,0,0}; cNH[rt] = f32x4{0,0,0,0};
    }
    if (s >= 1) {
      const int pr = (s + 1) & 1;
      const bf16_t* h1src = h1b + pr * (kB * kH);
#pragma unroll
      for (int kc = 0; kc < 16; ++kc) {
        bf16x8 a0 = ld16x<XL>(h1src + ar0 + kc * 32 + koff);
        bf16x8 a1 = ld16x<XL>(h1src + ar1 + kc * 32 + koff);
        cR[0]  = MFMA(a0, fh[0][kc], cR[0], 0,0,0);
        cR[1]  = MFMA(a1, fh[0][kc], cR[1], 0,0,0);
        cZ[0]  = MFMA(a0, fh[1][kc], cZ[0], 0,0,0);
        cZ[1]  = MFMA(a1, fh[1][kc], cZ[1], 0,0,0);
        cNH[0] = MFMA(a0, fh[2][kc], cNH[0],0,0,0);
        cNH[1] = MFMA(a1, fh[2][kc], cNH[1],0,0,0);
      }
    }
    __syncthreads();  // P: w3's partials visible
    if (s >= 1) {
      const int pw = s & 1;
      bf16_t* hnb = h1b + pw * (kB * kH);
#pragma unroll
      for (int rt = 0; rt < 2; ++rt) {
        f32x4 pR  = *(const f32x4*)(part + ((rt * 3 + 0) * 64 + lane) * 4);
        f32x4 pZ  = *(const f32x4*)(part + ((rt * 3 + 1) * 64 + lane) * 4);
        f32x4 pNX = *(const f32x4*)(part + ((rt * 3 + 2) * 64 + lane) * 4);
#pragma unroll
        for (int i = 0; i < 4; ++i) {
          const int row = rbase + rt * 16 + lq * 4 + i;
          float r = sigmoid_f(cR[rt][i] + pR[i] + b1r);
          float z = sigmoid_f(cZ[rt][i] + pZ[i] + b1z);
          float n = tanh_f((pNX[i] + b1nx) + r * (cNH[rt][i] + b1nh));
          float hn = (1.f - z) * n + z * h1m[rt][i];
          h1m[rt][i] = hn;
          if (s < kT) st2x<XL>(hnb + row * kH + c, hn);
          else        h1f[row * kH + c] = hn;  // final hidden for the head
        }
      }
    }
    __syncthreads();  // A
    __syncthreads();  // B
    if constexpr (XL) asm volatile("buffer_inv" ::: "memory");
  }
}

// ---- role: layer 1 x-part (both row tiles) -> LDS partials ----
template <bool XL>
__device__ __attribute__((noinline)) void role_l1x(
    bf16_t* __restrict__ h0b, const bf16_t* __restrict__ w1s,
    float* __restrict__ part, int lane, int rbase) {
  const int lm = lane & 15, lq = lane >> 4, koff = lq * 8;
  const int ar0 = (rbase + lm) * kH, ar1 = (rbase + 16 + lm) * kH;
  bf16x8 fx[3][16];  // 48 frags = 192 VGPR
#pragma unroll
  for (int g = 0; g < 3; ++g)
#pragma unroll
    for (int kc = 0; kc < 16; ++kc) fx[g][kc] = FRAG1(g + 3, kc);

  for (int s = 0; s <= kT; ++s) {
    if (s >= 1) {
      const int pr = (s + 1) & 1;
      const bf16_t* xsrc = h0b + pr * (kB * kH);
      f32x4 xR[2], xZ[2], xNX[2];
#pragma unroll
      for (int rt = 0; rt < 2; ++rt) {
        xR[rt] = f32x4{0,0,0,0}; xZ[rt] = f32x4{0,0,0,0}; xNX[rt] = f32x4{0,0,0,0};
      }
#pragma unroll
      for (int kc = 0; kc < 16; ++kc) {
        bf16x8 a0 = ld16x<XL>(xsrc + ar0 + kc * 32 + koff);
        bf16x8 a1 = ld16x<XL>(xsrc + ar1 + kc * 32 + koff);
        xR[0]  = MFMA(a0, fx[0][kc], xR[0], 0,0,0);
        xR[1]  = MFMA(a1, fx[0][kc], xR[1], 0,0,0);
        xZ[0]  = MFMA(a0, fx[1][kc], xZ[0], 0,0,0);
        xZ[1]  = MFMA(a1, fx[1][kc], xZ[1], 0,0,0);
        xNX[0] = MFMA(a0, fx[2][kc], xNX[0],0,0,0);
        xNX[1] = MFMA(a1, fx[2][kc], xNX[1],0,0,0);
      }
#pragma unroll
      for (int rt = 0; rt < 2; ++rt) {
        *(f32x4*)(part + ((rt * 3 + 0) * 64 + lane) * 4) = xR[rt];
        *(f32x4*)(part + ((rt * 3 + 1) * 64 + lane) * 4) = xZ[rt];
        *(f32x4*)(part + ((rt * 3 + 2) * 64 + lane) * 4) = xNX[rt];
      }
    }
    __syncthreads();  // P
    __syncthreads();  // A
    __syncthreads();  // B
    if constexpr (XL) asm volatile("buffer_inv" ::: "memory");
  }
}

__launch_bounds__(NTHR, 1)
__global__ void gru_persistent(
    const float* __restrict__ seq,
    const float* __restrict__ Wih0, const float* __restrict__ Whh0,
    const float* __restrict__ bih0, const float* __restrict__ bhh0,
    const float* __restrict__ Wih1, const float* __restrict__ Whh1,
    const float* __restrict__ bih1, const float* __restrict__ bhh1,
    char* __restrict__ ws) {
  extern __shared__ char smem[];
  bf16_t* w0s = (bf16_t*)smem;
  bf16_t* w1s = (bf16_t*)(smem + L0F * 512 * 2);
  float*  part = (float*)(smem + PART_OFF);
  __shared__ unsigned sh_enc;

  const int tid = threadIdx.x;

  // ---- self-organization: group = physical XCD, slot = per-XCD ordinal ----
  if (tid == 0) {
    unsigned xcd;
    asm("s_getreg_b32 %0, hwreg(HW_REG_XCC_ID)" : "=s"(xcd));
    xcd &= 7;
    unsigned* cnt   = (unsigned*)(ws + WS_CNT) + xcd * 32;
    unsigned* total = (unsigned*)(ws + WS_TOTAL);
    unsigned* fb    = (unsigned*)(ws + WS_FB);
    unsigned slot = __hip_atomic_fetch_add(cnt, 1u, __ATOMIC_RELAXED,
                                           __HIP_MEMORY_SCOPE_AGENT);
    if (slot >= 32)
      __hip_atomic_store(fb, 1u, __ATOMIC_RELAXED, __HIP_MEMORY_SCOPE_AGENT);
    __hip_atomic_fetch_add(total, 1u, __ATOMIC_RELAXED,
                           __HIP_MEMORY_SCOPE_AGENT);
    long guard = 0;
    while (__hip_atomic_load(total, __ATOMIC_RELAXED,
                             __HIP_MEMORY_SCOPE_AGENT) < (unsigned)GBLK) {
      __builtin_amdgcn_s_sleep(1);
      if (++guard > (1L << 24)) break;
    }
    unsigned f = __hip_atomic_load(fb, __ATOMIC_RELAXED,
                                   __HIP_MEMORY_SCOPE_AGENT);
    sh_enc = (f << 31) | (xcd << 8) | (slot & 255);
  }
  __syncthreads();
  const unsigned enc = sh_enc;
  const bool fallback = (enc >> 31) != 0;
  const int g    = fallback ? (blockIdx.x & 7)  : (int)((enc >> 8) & 7);
  const int slot = fallback ? (blockIdx.x >> 3) : (int)(enc & 255);
  const int hs   = slot * HB;

  // ---- stage weights into fragment-major LDS (bf16) ----
  for (int idx = tid; idx < L0F * 512; idx += NTHR) {
    const int j = idx & 7, l = (idx >> 3) & 63, rest = idx >> 9;
    const int kc = rest % 17, gg = rest / 17;
    const int col = hs + (l & 15);
    const int k = kc * 32 + (l >> 4) * 8 + j;
    const int row = gg * kH + col;
    float v = (k < kH) ? Whh0[row * kH + k] : Wih0[row * kF + (k - kH)];
    w0s[idx] = (bf16_t)v;
  }
  for (int idx = tid; idx < L1F * 512; idx += NTHR) {
    const int j = idx & 7, l = (idx >> 3) & 63, rest = idx >> 9;
    const int kc = rest & 15, gg = rest >> 4;
    const int col = hs + (l & 15);
    const int k = kc * 32 + (l >> 4) * 8 + j;
    const int row = (gg % 3) * kH + col;
    float v = (gg < 3) ? Whh1[row * kH + k] : Wih1[row * kH + k];
    w1s[idx] = (bf16_t)v;
  }

  const int lm = tid & 15;
  const int c = hs + lm;
  const float b0r  = bih0[c] + bhh0[c];
  const float b0z  = bih0[kH + c] + bhh0[kH + c];
  const float b0nx = bih0[2 * kH + c];
  const float b0nh = bhh0[2 * kH + c];
  const float b1r  = bih1[c] + bhh1[c];
  const float b1z  = bih1[kH + c] + bhh1[kH + c];
  const float b1nx = bih1[2 * kH + c];
  const float b1nh = bhh1[2 * kH + c];

  __syncthreads();  // staging complete

  bf16_t* h0b = (bf16_t*)(ws + WS_H0B);
  bf16_t* h1b = (bf16_t*)(ws + WS_H1B);
  float*  h1f = (float*)(ws + WS_H1F);
  unsigned* flg = (unsigned*)(ws + WS_FLG) + g * 1024;  // 32 lines x 128B
  const int wv   = tid >> 6;
  const int lane = tid & 63;
  const int rbase = g * RG;

  if (!fallback) {
    if (wv == 0)
      role_l0<true>(seq, h0b, flg, w0s, slot, true, lane, rbase, 0, c,
                    b0r, b0z, b0nx, b0nh);
    else if (wv == 2)
      role_l0<true>(seq, h0b, flg, w0s, slot, false, lane, rbase, 1, c,
                    b0r, b0z, b0nx, b0nh);
    else if (wv == 1)
      role_l1h<true>(h1b, h1f, w1s, part, lane, rbase, c,
                     b1r, b1z, b1nx, b1nh);
    else
      role_l1x<true>(h0b, w1s, part, lane, rbase);
  } else {
    if (wv == 0)
      role_l0<false>(seq, h0b, flg, w0s, slot, true, lane, rbase, 0, c,
                     b0r, b0z, b0nx, b0nh);
    else if (wv == 2)
      role_l0<false>(seq, h0b, flg, w0s, slot, false, lane, rbase, 1, c,
                     b0r, b0z, b0nx, b0nh);
    else if (wv == 1)
      role_l1h<false>(h1b, h1f, w1s, part, lane, rbase, c,
                      b1r, b1z, b1nx, b1nh);
    else
      role_l1x<false>(h0b, w1s, part, lane, rbase);
  }
}

// ---- head: concat(h1_last, embed) -> fc1+relu -> fc2 ----
__global__ void head_kernel(const float* __restrict__ h1,
                            const int* __restrict__ ticker,
                            const float* __restrict__ etab,
                            const float* __restrict__ fc1w,
                            const float* __restrict__ fc1b,
                            const float* __restrict__ fc2w,
                            const float* __restrict__ fc2b,
                            float* __restrict__ out) {
  __shared__ float xin[4][kH + kE];
  __shared__ float y1[4][kH];
  const int tid = threadIdx.x;
  const int b0 = blockIdx.x * 4;

  for (int idx = tid; idx < 4 * (kH + kE); idx += 256) {
    const int r = idx / (kH + kE), k = idx % (kH + kE);
    const int b = b0 + r;
    xin[r][k] = (k < kH) ? h1[b * kH + k] : etab[ticker[b] * kE + (k - kH)];
  }
  __syncthreads();

#pragma unroll
  for (int jj = 0; jj < 2; ++jj) {
    const int j = tid + jj * 256;
    const float* wr = fc1w + j * (kH + kE);
    float a0 = 0.f, a1 = 0.f, a2 = 0.f, a3 = 0.f;
    for (int k = 0; k < kH + kE; ++k) {
      const float w = wr[k];
      a0 += w * xin[0][k];
      a1 += w * xin[1][k];
      a2 += w * xin[2][k];
      a3 += w * xin[3][k];
    }
    const float bb = fc1b[j];
    y1[0][j] = fmaxf(a0 + bb, 0.f);
    y1[1][j] = fmaxf(a1 + bb, 0.f);
    y1[2][j] = fmaxf(a2 + bb, 0.f);
    y1[3][j] = fmaxf(a3 + bb, 0.f);
  }
  __syncthreads();

  if (tid < 4 * kPD) {
    const int r = tid / kPD, j = tid % kPD;
    const float* wr = fc2w + j * kH;
    float acc = fc2b[j];
    for (int k = 0; k < kH; ++k) acc += wr[k] * y1[r][k];
    out[(b0 + r) * kPD + j] = acc;
  }
}

extern "C" void kernel_launch(void* const* d_in, const int* in_sizes, int n_in,
                              void* d_out, int out_size, void* d_ws,
                              size_t ws_size, hipStream_t stream) {
  (void)in_sizes; (void)n_in; (void)out_size; (void)ws_size;

  const int*   ticker = (const int*)d_in[0];
  const float* seq    = (const float*)d_in[1];
  const float* etab   = (const float*)d_in[2];
  const float* Wih0   = (const float*)d_in[3];
  const float* Whh0   = (const float*)d_in[4];
  const float* bih0   = (const float*)d_in[5];
  const float* bhh0   = (const float*)d_in[6];
  const float* Wih1   = (const float*)d_in[7];
  const float* Whh1   = (const float*)d_in[8];
  const float* bih1   = (const float*)d_in[9];
  const float* bhh1   = (const float*)d_in[10];
  const float* fc1w   = (const float*)d_in[11];
  const float* fc1b   = (const float*)d_in[12];
  const float* fc2w   = (const float*)d_in[13];
  const float* fc2b   = (const float*)d_in[14];

  char* ws = (char*)d_ws;
  (void)hipMemsetAsync(ws, 0, WS_INIT, stream);  // counters + flags + h0b/h1b

  gru_persistent<<<GBLK, NTHR, LDSB, stream>>>(
      seq, Wih0, Whh0, bih0, bhh0, Wih1, Whh1, bih1, bhh1, ws);

  head_kernel<<<kB / 4, 256, 0, stream>>>((const float*)(ws + WS_H1F), ticker,
                                          etab, fc1w, fc1b, fc2w, fc2b,
                                          (float*)d_out);
}

// Round 9
// 3287.354 us; speedup vs baseline: 2.3358x; 1.0518x over previous
//
#include <hip/hip_runtime.h>
#include <hip/hip_bf16.h>

// ---------------------------------------------------------------------------
// Persistent fused 2-layer GRU + head for MI355X (gfx950).
//
// R8 -> R9 (theory: step time is inflated ~5x by DVFS floor-clock; s_sleep
// in every spin is a power-nap hint and 256 CUs sleep ~80% of each step):
//  * BUSY-SPIN (no s_sleep) in all steady-state polls. Startup/fallback
//    paths keep s_sleep (run once / emergency only).
//  * 3 -> 2 __syncthreads per step; barrier manager moved to w1 (whose
//    stores are last): compute -> P -> w1: epilogue+store+vmcnt(0)+flag+
//    poll -> B -> buffer_inv. R5-proven flag protocol otherwise unchanged.
//  * Register-resident weight fragments, XCD-local exchange, self-assign
//    + MALL fallback: all unchanged from R8.
// ---------------------------------------------------------------------------

namespace {
constexpr int kB  = 256;   // batch
constexpr int kT  = 512;   // time steps
constexpr int kF  = 32;    // input features
constexpr int kH  = 512;   // hidden
constexpr int kE  = 32;    // embed dim
constexpr int kPD = 30;    // predict days

constexpr int GBLK = 256;  // 8 XCD groups x 32 hidden slots, 1 block/CU
constexpr int NTHR = 256;  // 4 waves
constexpr int RG   = 32;   // batch rows per group
constexpr int HB   = 16;   // hidden cols per block

// fragment-major weight staging LDS + fp32 partial-handoff buffer
constexpr int L0F  = 3 * 17;
constexpr int L1F  = 6 * 16;
constexpr int PART_OFF = (L0F + L1F) * 512 * 2;   // 150528 B
constexpr int LDSB = PART_OFF + 6 * 64 * 16;      // +6KB partials = 156672
static_assert(LDSB <= 160 * 1024, "LDS overflow");

// ws layout (bytes)
constexpr size_t WS_CNT   = 0;        // 8 per-XCD counters, 128B apart
constexpr size_t WS_TOTAL = 1024;     // arrival counter
constexpr size_t WS_FB    = 1152;     // fallback flag
constexpr size_t WS_FLG   = 2048;     // 8 groups x 32 slots x 128B = 32KB
constexpr size_t WS_H0B   = 65536;                    // 2*B*H bf16 = 512KB
constexpr size_t WS_H1B   = WS_H0B + 2 * kB * kH * 2; // 512KB
constexpr size_t WS_H1F   = WS_H0B + 4 * kB * kH * 2; // B*H f32 = 512KB
constexpr size_t WS_INIT  = WS_H1F;   // zero [0, WS_H1F)

typedef __bf16 bf16_t;
typedef __bf16 bf16x8 __attribute__((ext_vector_type(8)));
typedef float  f32x4  __attribute__((ext_vector_type(4)));

#define MFMA __builtin_amdgcn_mfma_f32_16x16x32_bf16

__device__ __forceinline__ float sigmoid_f(float x) {
  return 1.f / (1.f + __expf(-x));
}
__device__ __forceinline__ float tanh_f(float x) {
  float a = fabsf(x);
  float e = __expf(-2.f * a);
  float t = (1.f - e) / (1.f + e);
  return copysignf(t, x);
}

// MALL-coherent primitives (fallback path only)
__device__ __forceinline__ bf16x8 ld16_mall(const bf16_t* p) {
  const unsigned long long* q = (const unsigned long long*)p;
  unsigned long long lo =
      __hip_atomic_load(q, __ATOMIC_RELAXED, __HIP_MEMORY_SCOPE_AGENT);
  unsigned long long hi =
      __hip_atomic_load(q + 1, __ATOMIC_RELAXED, __HIP_MEMORY_SCOPE_AGENT);
  union { unsigned long long u[2]; bf16x8 v; } x;
  x.u[0] = lo; x.u[1] = hi;
  return x.v;
}
__device__ __forceinline__ void st2_mall(bf16_t* p, float v) {
  bf16_t b = (bf16_t)v;
  unsigned short bits = __builtin_bit_cast(unsigned short, b);
  __hip_atomic_store((unsigned short*)p, bits, __ATOMIC_RELAXED,
                     __HIP_MEMORY_SCOPE_AGENT);
}

template <bool XL>
__device__ __forceinline__ bf16x8 ld16x(const bf16_t* p) {
  if constexpr (XL) return *(const bf16x8*)p;
  else return ld16_mall(p);
}
template <bool XL>
__device__ __forceinline__ void st2x(bf16_t* p, float v) {
  if constexpr (XL) *p = (bf16_t)v;
  else st2_mall(p, v);
}

__device__ __forceinline__ void drain_stores() {
  asm volatile("s_waitcnt vmcnt(0)" ::: "memory");
}

// R5-proven inter-block barrier, minus s_sleep (busy spin keeps clocks up):
// store own flag, poll all 32 group flags (one per lane, 128B apart) with
// buffer_inv before each volatile load.
template <bool XL>
__device__ __forceinline__ void block_flag_barrier(unsigned* flg, int slot,
                                                   int lane, unsigned tgt) {
  if constexpr (XL) {
    if (lane == 0) *(volatile unsigned*)(flg + slot * 32) = tgt;
    volatile unsigned* fp = flg + (lane & 31) * 32;
    long guard = 0;
    for (;;) {
      asm volatile("buffer_inv" ::: "memory");
      unsigned v = *fp;
      if (__all((int)(v >= tgt))) break;
      if (++guard > (1L << 22)) break;  // co-residency guaranteed
    }
  } else {
    if (lane == 0)
      __hip_atomic_store(flg + slot * 32, tgt, __ATOMIC_RELAXED,
                         __HIP_MEMORY_SCOPE_AGENT);
    unsigned* fp = flg + (lane & 31) * 32;
    long guard = 0;
    for (;;) {
      unsigned v = __hip_atomic_load(fp, __ATOMIC_RELAXED,
                                     __HIP_MEMORY_SCOPE_AGENT);
      if (__all((int)(v >= tgt))) break;
      __builtin_amdgcn_s_sleep(1);  // emergency path only
      if (++guard > (1L << 20)) break;
    }
  }
}
}  // namespace

#define FRAG0(gg, kc) (*(const bf16x8*)(w0s + (((gg)*17 + (kc)) * 64 + lane) * 8))
#define FRAG1(gg, kc) (*(const bf16x8*)(w1s + (((gg)*16 + (kc)) * 64 + lane) * 8))

// ---- role: layer 0, one row tile (waves 0 and 2) ----
template <bool XL>
__device__ __attribute__((noinline)) void role_l0(
    const float* __restrict__ seq, bf16_t* __restrict__ h0b,
    const bf16_t* __restrict__ w0s, int lane, int rbase, int rt, int c,
    float b0r, float b0z, float b0nx, float b0nh) {
  const int lm = lane & 15, lq = lane >> 4, koff = lq * 8;
  const int arow = rbase + rt * 16 + lm;
  const int ar = arow * kH;
  bf16x8 f0[3][17];  // 51 frags = 204 VGPR, loaded once
#pragma unroll
  for (int g = 0; g < 3; ++g)
#pragma unroll
    for (int kc = 0; kc < 17; ++kc) f0[g][kc] = FRAG0(g, kc);
  float h0m[4] = {0.f, 0.f, 0.f, 0.f};

  for (int s = 0; s <= kT; ++s) {
    if (s < kT) {
      const int pr = (s + 1) & 1, pw = s & 1;
      const bf16_t* hsrc = h0b + pr * (kB * kH);
      f32x4 aR{0,0,0,0}, aZ{0,0,0,0}, aNH{0,0,0,0}, aNX{0,0,0,0};
#pragma unroll
      for (int kc = 0; kc < 16; ++kc) {
        bf16x8 a = ld16x<XL>(hsrc + ar + kc * 32 + koff);
        aR  = MFMA(a, f0[0][kc], aR, 0, 0, 0);
        aZ  = MFMA(a, f0[1][kc], aZ, 0, 0, 0);
        aNH = MFMA(a, f0[2][kc], aNH, 0, 0, 0);
      }
      {
        const float* xp = seq + ((size_t)arow * kT + s) * kF + koff;
        bf16x8 ax;
#pragma unroll
        for (int j = 0; j < 8; ++j) ax[j] = (bf16_t)xp[j];
        aR  = MFMA(ax, f0[0][16], aR, 0, 0, 0);
        aZ  = MFMA(ax, f0[1][16], aZ, 0, 0, 0);
        aNX = MFMA(ax, f0[2][16], aNX, 0, 0, 0);
      }
      bf16_t* hnb = h0b + pw * (kB * kH);
#pragma unroll
      for (int i = 0; i < 4; ++i) {
        const int row = rbase + rt * 16 + lq * 4 + i;
        float r = sigmoid_f(aR[i] + b0r);
        float z = sigmoid_f(aZ[i] + b0z);
        float n = tanh_f((aNX[i] + b0nx) + r * (aNH[i] + b0nh));
        float hn = (1.f - z) * n + z * h0m[i];
        h0m[i] = hn;
        st2x<XL>(hnb + row * kH + c, hn);
      }
    }
    __syncthreads();  // P (stores drained by barrier-implied waitcnt)
    __syncthreads();  // B (w1 runs the inter-block barrier in between)
    if constexpr (XL) asm volatile("buffer_inv" ::: "memory");
  }
}

// ---- role: layer 1 h-part + epilogue + INTER-BLOCK BARRIER (wave 1) ----
template <bool XL>
__device__ __attribute__((noinline)) void role_l1h(
    bf16_t* __restrict__ h1b, float* __restrict__ h1f,
    unsigned* __restrict__ flg, int slot, const bf16_t* __restrict__ w1s,
    const float* __restrict__ part, int lane, int rbase, int c, float b1r,
    float b1z, float b1nx, float b1nh) {
  const int lm = lane & 15, lq = lane >> 4, koff = lq * 8;
  const int ar0 = (rbase + lm) * kH, ar1 = (rbase + 16 + lm) * kH;
  bf16x8 fh[3][16];  // 48 frags = 192 VGPR
#pragma unroll
  for (int g = 0; g < 3; ++g)
#pragma unroll
    for (int kc = 0; kc < 16; ++kc) fh[g][kc] = FRAG1(g, kc);
  float h1m[2][4] = {{0,0,0,0},{0,0,0,0}};

  for (int s = 0; s <= kT; ++s) {
    f32x4 cR[2], cZ[2], cNH[2];
#pragma unroll
    for (int rt = 0; rt < 2; ++rt) {
      cR[rt] = f32x4{0,0,0,0}; cZ[rt] = f32x4{0,0,0,0}; cNH[rt] = f32x4{0,0,0,0};
    }
    if (s >= 1) {
      const int pr = (s + 1) & 1;
      const bf16_t* h1src = h1b + pr * (kB * kH);
#pragma unroll
      for (int kc = 0; kc < 16; ++kc) {
        bf16x8 a0 = ld16x<XL>(h1src + ar0 + kc * 32 + koff);
        bf16x8 a1 = ld16x<XL>(h1src + ar1 + kc * 32 + koff);
        cR[0]  = MFMA(a0, fh[0][kc], cR[0], 0,0,0);
        cR[1]  = MFMA(a1, fh[0][kc], cR[1], 0,0,0);
        cZ[0]  = MFMA(a0, fh[1][kc], cZ[0], 0,0,0);
        cZ[1]  = MFMA(a1, fh[1][kc], cZ[1], 0,0,0);
        cNH[0] = MFMA(a0, fh[2][kc], cNH[0],0,0,0);
        cNH[1] = MFMA(a1, fh[2][kc], cNH[1],0,0,0);
      }
    }
    __syncthreads();  // P: w3's partials visible; w0/w2/w3 stores drained
    if (s >= 1) {
      const int pw = s & 1;
      bf16_t* hnb = h1b + pw * (kB * kH);
#pragma unroll
      for (int rt = 0; rt < 2; ++rt) {
        f32x4 pR  = *(const f32x4*)(part + ((rt * 3 + 0) * 64 + lane) * 4);
        f32x4 pZ  = *(const f32x4*)(part + ((rt * 3 + 1) * 64 + lane) * 4);
        f32x4 pNX = *(const f32x4*)(part + ((rt * 3 + 2) * 64 + lane) * 4);
#pragma unroll
        for (int i = 0; i < 4; ++i) {
          const int row = rbase + rt * 16 + lq * 4 + i;
          float r = sigmoid_f(cR[rt][i] + pR[i] + b1r);
          float z = sigmoid_f(cZ[rt][i] + pZ[i] + b1z);
          float n = tanh_f((pNX[i] + b1nx) + r * (cNH[rt][i] + b1nh));
          float hn = (1.f - z) * n + z * h1m[rt][i];
          h1m[rt][i] = hn;
          if (s < kT) st2x<XL>(hnb + row * kH + c, hn);
          else        h1f[row * kH + c] = hn;  // final hidden for the head
        }
      }
    }
    if (s < kT) {
      drain_stores();  // own h1b stores visible in L2 before flagging
      block_flag_barrier<XL>(flg, slot, lane, (unsigned)(s + 1));
    }
    __syncthreads();  // B
    if constexpr (XL) asm volatile("buffer_inv" ::: "memory");
  }
}

// ---- role: layer 1 x-part -> LDS partials (wave 3) ----
template <bool XL>
__device__ __attribute__((noinline)) void role_l1x(
    bf16_t* __restrict__ h0b, const bf16_t* __restrict__ w1s,
    float* __restrict__ part, int lane, int rbase) {
  const int lm = lane & 15, lq = lane >> 4, koff = lq * 8;
  (void)lq;
  const int ar0 = (rbase + lm) * kH, ar1 = (rbase + 16 + lm) * kH;
  bf16x8 fx[3][16];  // 48 frags = 192 VGPR
#pragma unroll
  for (int g = 0; g < 3; ++g)
#pragma unroll
    for (int kc = 0; kc < 16; ++kc) fx[g][kc] = FRAG1(g + 3, kc);

  for (int s = 0; s <= kT; ++s) {
    if (s >= 1) {
      const int pr = (s + 1) & 1;
      const bf16_t* xsrc = h0b + pr * (kB * kH);
      f32x4 xR[2], xZ[2], xNX[2];
#pragma unroll
      for (int rt = 0; rt < 2; ++rt) {
        xR[rt] = f32x4{0,0,0,0}; xZ[rt] = f32x4{0,0,0,0}; xNX[rt] = f32x4{0,0,0,0};
      }
#pragma unroll
      for (int kc = 0; kc < 16; ++kc) {
        bf16x8 a0 = ld16x<XL>(xsrc + ar0 + kc * 32 + koff);
        bf16x8 a1 = ld16x<XL>(xsrc + ar1 + kc * 32 + koff);
        xR[0]  = MFMA(a0, fx[0][kc], xR[0], 0,0,0);
        xR[1]  = MFMA(a1, fx[0][kc], xR[1], 0,0,0);
        xZ[0]  = MFMA(a0, fx[1][kc], xZ[0], 0,0,0);
        xZ[1]  = MFMA(a1, fx[1][kc], xZ[1], 0,0,0);
        xNX[0] = MFMA(a0, fx[2][kc], xNX[0],0,0,0);
        xNX[1] = MFMA(a1, fx[2][kc], xNX[1],0,0,0);
      }
#pragma unroll
      for (int rt = 0; rt < 2; ++rt) {
        *(f32x4*)(part + ((rt * 3 + 0) * 64 + lane) * 4) = xR[rt];
        *(f32x4*)(part + ((rt * 3 + 1) * 64 + lane) * 4) = xZ[rt];
        *(f32x4*)(part + ((rt * 3 + 2) * 64 + lane) * 4) = xNX[rt];
      }
    }
    __syncthreads();  // P
    __syncthreads();  // B
    if constexpr (XL) asm volatile("buffer_inv" ::: "memory");
  }
}

__launch_bounds__(NTHR, 1)
__global__ void gru_persistent(
    const float* __restrict__ seq,
    const float* __restrict__ Wih0, const float* __restrict__ Whh0,
    const float* __restrict__ bih0, const float* __restrict__ bhh0,
    const float* __restrict__ Wih1, const float* __restrict__ Whh1,
    const float* __restrict__ bih1, const float* __restrict__ bhh1,
    char* __restrict__ ws) {
  extern __shared__ char smem[];
  bf16_t* w0s = (bf16_t*)smem;
  bf16_t* w1s = (bf16_t*)(smem + L0F * 512 * 2);
  float*  part = (float*)(smem + PART_OFF);
  __shared__ unsigned sh_enc;

  const int tid = threadIdx.x;

  // ---- self-organization: group = physical XCD, slot = per-XCD ordinal ----
  if (tid == 0) {
    unsigned xcd;
    asm("s_getreg_b32 %0, hwreg(HW_REG_XCC_ID)" : "=s"(xcd));
    xcd &= 7;
    unsigned* cnt   = (unsigned*)(ws + WS_CNT) + xcd * 32;
    unsigned* total = (unsigned*)(ws + WS_TOTAL);
    unsigned* fb    = (unsigned*)(ws + WS_FB);
    unsigned slot = __hip_atomic_fetch_add(cnt, 1u, __ATOMIC_RELAXED,
                                           __HIP_MEMORY_SCOPE_AGENT);
    if (slot >= 32)
      __hip_atomic_store(fb, 1u, __ATOMIC_RELAXED, __HIP_MEMORY_SCOPE_AGENT);
    __hip_atomic_fetch_add(total, 1u, __ATOMIC_RELAXED,
                           __HIP_MEMORY_SCOPE_AGENT);
    long guard = 0;
    while (__hip_atomic_load(total, __ATOMIC_RELAXED,
                             __HIP_MEMORY_SCOPE_AGENT) < (unsigned)GBLK) {
      __builtin_amdgcn_s_sleep(1);  // one-time startup: sleep is fine here
      if (++guard > (1L << 24)) break;
    }
    unsigned f = __hip_atomic_load(fb, __ATOMIC_RELAXED,
                                   __HIP_MEMORY_SCOPE_AGENT);
    sh_enc = (f << 31) | (xcd << 8) | (slot & 255);
  }
  __syncthreads();
  const unsigned enc = sh_enc;
  const bool fallback = (enc >> 31) != 0;
  const int g    = fallback ? (blockIdx.x & 7)  : (int)((enc >> 8) & 7);
  const int slot = fallback ? (blockIdx.x >> 3) : (int)(enc & 255);
  const int hs   = slot * HB;

  // ---- stage weights into fragment-major LDS (bf16) ----
  for (int idx = tid; idx < L0F * 512; idx += NTHR) {
    const int j = idx & 7, l = (idx >> 3) & 63, rest = idx >> 9;
    const int kc = rest % 17, gg = rest / 17;
    const int col = hs + (l & 15);
    const int k = kc * 32 + (l >> 4) * 8 + j;
    const int row = gg * kH + col;
    float v = (k < kH) ? Whh0[row * kH + k] : Wih0[row * kF + (k - kH)];
    w0s[idx] = (bf16_t)v;
  }
  for (int idx = tid; idx < L1F * 512; idx += NTHR) {
    const int j = idx & 7, l = (idx >> 3) & 63, rest = idx >> 9;
    const int kc = rest & 15, gg = rest >> 4;
    const int col = hs + (l & 15);
    const int k = kc * 32 + (l >> 4) * 8 + j;
    const int row = (gg % 3) * kH + col;
    float v = (gg < 3) ? Whh1[row * kH + k] : Wih1[row * kH + k];
    w1s[idx] = (bf16_t)v;
  }

  const int lm = tid & 15;
  const int c = hs + lm;
  const float b0r  = bih0[c] + bhh0[c];
  const float b0z  = bih0[kH + c] + bhh0[kH + c];
  const float b0nx = bih0[2 * kH + c];
  const float b0nh = bhh0[2 * kH + c];
  const float b1r  = bih1[c] + bhh1[c];
  const float b1z  = bih1[kH + c] + bhh1[kH + c];
  const float b1nx = bih1[2 * kH + c];
  const float b1nh = bhh1[2 * kH + c];

  __syncthreads();  // staging complete

  bf16_t* h0b = (bf16_t*)(ws + WS_H0B);
  bf16_t* h1b = (bf16_t*)(ws + WS_H1B);
  float*  h1f = (float*)(ws + WS_H1F);
  unsigned* flg = (unsigned*)(ws + WS_FLG) + g * 1024;  // 32 lines x 128B
  const int wv   = tid >> 6;
  const int lane = tid & 63;
  const int rbase = g * RG;

  if (!fallback) {
    if (wv == 0)
      role_l0<true>(seq, h0b, w0s, lane, rbase, 0, c, b0r, b0z, b0nx, b0nh);
    else if (wv == 2)
      role_l0<true>(seq, h0b, w0s, lane, rbase, 1, c, b0r, b0z, b0nx, b0nh);
    else if (wv == 1)
      role_l1h<true>(h1b, h1f, flg, slot, w1s, part, lane, rbase, c,
                     b1r, b1z, b1nx, b1nh);
    else
      role_l1x<true>(h0b, w1s, part, lane, rbase);
  } else {
    if (wv == 0)
      role_l0<false>(seq, h0b, w0s, lane, rbase, 0, c, b0r, b0z, b0nx, b0nh);
    else if (wv == 2)
      role_l0<false>(seq, h0b, w0s, lane, rbase, 1, c, b0r, b0z, b0nx, b0nh);
    else if (wv == 1)
      role_l1h<false>(h1b, h1f, flg, slot, w1s, part, lane, rbase, c,
                      b1r, b1z, b1nx, b1nh);
    else
      role_l1x<false>(h0b, w1s, part, lane, rbase);
  }
}

// ---- head: concat(h1_last, embed) -> fc1+relu -> fc2 ----
__global__ void head_kernel(const float* __restrict__ h1,
                            const int* __restrict__ ticker,
                            const float* __restrict__ etab,
                            const float* __restrict__ fc1w,
                            const float* __restrict__ fc1b,
                            const float* __restrict__ fc2w,
                            const float* __restrict__ fc2b,
                            float* __restrict__ out) {
  __shared__ float xin[4][kH + kE];
  __shared__ float y1[4][kH];
  const int tid = threadIdx.x;
  const int b0 = blockIdx.x * 4;

  for (int idx = tid; idx < 4 * (kH + kE); idx += 256) {
    const int r = idx / (kH + kE), k = idx % (kH + kE);
    const int b = b0 + r;
    xin[r][k] = (k < kH) ? h1[b * kH + k] : etab[ticker[b] * kE + (k - kH)];
  }
  __syncthreads();

#pragma unroll
  for (int jj = 0; jj < 2; ++jj) {
    const int j = tid + jj * 256;
    const float* wr = fc1w + j * (kH + kE);
    float a0 = 0.f, a1 = 0.f, a2 = 0.f, a3 = 0.f;
    for (int k = 0; k < kH + kE; ++k) {
      const float w = wr[k];
      a0 += w * xin[0][k];
      a1 += w * xin[1][k];
      a2 += w * xin[2][k];
      a3 += w * xin[3][k];
    }
    const float bb = fc1b[j];
    y1[0][j] = fmaxf(a0 + bb, 0.f);
    y1[1][j] = fmaxf(a1 + bb, 0.f);
    y1[2][j] = fmaxf(a2 + bb, 0.f);
    y1[3][j] = fmaxf(a3 + bb, 0.f);
  }
  __syncthreads();

  if (tid < 4 * kPD) {
    const int r = tid / kPD, j = tid % kPD;
    const float* wr = fc2w + j * kH;
    float acc = fc2b[j];
    for (int k = 0; k < kH; ++k) acc += wr[k] * y1[r][k];
    out[(b0 + r) * kPD + j] = acc;
  }
}

extern "C" void kernel_launch(void* const* d_in, const int* in_sizes, int n_in,
                              void* d_out, int out_size, void* d_ws,
                              size_t ws_size, hipStream_t stream) {
  (void)in_sizes; (void)n_in; (void)out_size; (void)ws_size;

  const int*   ticker = (const int*)d_in[0];
  const float* seq    = (const float*)d_in[1];
  const float* etab   = (const float*)d_in[2];
  const float* Wih0   = (const float*)d_in[3];
  const float* Whh0   = (const float*)d_in[4];
  const float* bih0   = (const float*)d_in[5];
  const float* bhh0   = (const float*)d_in[6];
  const float* Wih1   = (const float*)d_in[7];
  const float* Whh1   = (const float*)d_in[8];
  const float* bih1   = (const float*)d_in[9];
  const float* bhh1   = (const float*)d_in[10];
  const float* fc1w   = (const float*)d_in[11];
  const float* fc1b   = (const float*)d_in[12];
  const float* fc2w   = (const float*)d_in[13];
  const float* fc2b   = (const float*)d_in[14];

  char* ws = (char*)d_ws;
  (void)hipMemsetAsync(ws, 0, WS_INIT, stream);  // counters + flags + h0b/h1b

  gru_persistent<<<GBLK, NTHR, LDSB, stream>>>(
      seq, Wih0, Whh0, bih0, bhh0, Wih1, Whh1, bih1, bhh1, ws);

  head_kernel<<<kB / 4, 256, 0, stream>>>((const float*)(ws + WS_H1F), ticker,
                                          etab, fc1w, fc1b, fc2w, fc2b,
                                          (float*)d_out);
}